// Round 9
// baseline (207.756 us; speedup 1.0000x reference)
//
#include <hip/hip_runtime.h>
#include <hip/hip_bf16.h>
#include <math.h>

#define BB 4
#define MM 1024
#define RR 256
#define HH 16
#define DHH 64
#define DD (HH*DHH)   // 1024

typedef __attribute__((ext_vector_type(8))) short short8;   // 8 bf16 (MFMA A/B frag)
typedef __attribute__((ext_vector_type(4))) float f32x4;    // MFMA C/D frag

static __device__ __forceinline__ unsigned short f2bf(float x) {
    __hip_bfloat16 h = __float2bfloat16(x);
    return *(unsigned short*)&h;
}

#if defined(__has_builtin)
#  if __has_builtin(__builtin_amdgcn_exp2f)
#    define EXP2F(x) __builtin_amdgcn_exp2f(x)
#  endif
#endif
#ifndef EXP2F
#  define EXP2F(x) __expf((x) * 0.6931471805599453f)
#endif

// pack two fp32 -> bf16x2 via round-half-up + v_perm (3 VALU total)
static __device__ __forceinline__ unsigned pack_bf16_rh(float a, float b) {
    unsigned ua = __builtin_bit_cast(unsigned, a) + 0x8000u;
    unsigned ub = __builtin_bit_cast(unsigned, b) + 0x8000u;
    return __builtin_amdgcn_perm(ub, ua, 0x07060302u);   // {lo=ua[31:16], hi=ub[31:16]}
}

// async global->LDS DMA, 16B per lane; dest = wave-uniform base + lane*16 (linear!)
static __device__ __forceinline__ void gload_lds16(const void* g, void* l) {
    __builtin_amdgcn_global_load_lds(
        (const __attribute__((address_space(1))) unsigned int*)g,
        (__attribute__((address_space(3))) unsigned int*)l, 16, 0, 0);
}

// ---------------- Kernel A: prep = V-transpose (blocks 0..767) + P fp32->bf16 (rest) ----
__global__ __launch_bounds__(256) void prep_kernel(
    const float* __restrict__ Pq, const float* __restrict__ Pk, const float* __restrict__ Pv,
    const float* __restrict__ Vq, const float* __restrict__ Vk, const float* __restrict__ Vv,
    __hip_bfloat16* __restrict__ VTq, __hip_bfloat16* __restrict__ VTk,
    __hip_bfloat16* __restrict__ VTv, __hip_bfloat16* __restrict__ Pb)
{
    const int t = threadIdx.x;
    if (blockIdx.x < 768) {
        const int z   = blockIdx.x / 256;
        const int rem = blockIdx.x % 256;
        const int r0  = (rem & 7) * 32;
        const int d0  = (rem >> 3) * 32;
        const float* V = (z == 0) ? Vq : (z == 1) ? Vk : Vv;
        __hip_bfloat16* VT = (z == 0) ? VTq : (z == 1) ? VTk : VTv;

        __shared__ __hip_bfloat16 Ts[32][33];
        {
            const int row = t >> 3;
            const int c4  = (t & 7) * 4;
            float4 f = *(const float4*)&V[(size_t)(r0 + row) * DD + d0 + c4];
            Ts[row][c4 + 0] = __float2bfloat16(f.x);
            Ts[row][c4 + 1] = __float2bfloat16(f.y);
            Ts[row][c4 + 2] = __float2bfloat16(f.z);
            Ts[row][c4 + 3] = __float2bfloat16(f.w);
        }
        __syncthreads();
        {
            const int orow = t >> 3;
            const int oc4  = (t & 7) * 4;
            union { unsigned short u[4]; uint2 v; } pk;
            #pragma unroll
            for (int i = 0; i < 4; ++i) pk.u[i] = *(unsigned short*)&Ts[oc4 + i][orow];
            *(uint2*)&VT[(size_t)(d0 + orow) * RR + r0 + oc4] = pk.v;
        }
    } else {
        const size_t n4 = (size_t)BB * MM * RR / 4;
        size_t i = (size_t)(blockIdx.x - 768) * 256 + t;
        const int which = (int)(i / n4);
        const size_t off = i - (size_t)which * n4;
        const float* P = (which == 0) ? Pq : (which == 1) ? Pk : Pv;
        float4 f = *(const float4*)(P + off * 4);
        union { unsigned short u[4]; uint2 v; } pk;
        pk.u[0] = f2bf(f.x); pk.u[1] = f2bf(f.y); pk.u[2] = f2bf(f.z); pk.u[3] = f2bf(f.w);
        *(uint2*)((unsigned short*)Pb + (size_t)which * BB * MM * RR + off * 4) = pk.v;
    }
}

// ---------------- Kernel B: MFMA projection + bias + RoPE (round-0 version) ----------
__global__ __launch_bounds__(256) void svd_gemm(
    const __hip_bfloat16* __restrict__ Pb,
    const __hip_bfloat16* __restrict__ VTq, const __hip_bfloat16* __restrict__ VTk,
    const __hip_bfloat16* __restrict__ VTv,
    const float* __restrict__ bq, const float* __restrict__ bk, const float* __restrict__ bv,
    const int* __restrict__ pos_ids,
    __hip_bfloat16* __restrict__ qout, __hip_bfloat16* __restrict__ kout,
    __hip_bfloat16* __restrict__ vTout)
{
    const int which = blockIdx.z;
    const short* P = (const short*)Pb + (size_t)which * BB * MM * RR;
    const __hip_bfloat16* VT = (which == 0) ? VTq : (which == 1) ? VTk : VTv;
    const float* bias        = (which == 0) ? bq : (which == 1) ? bk : bv;

    const int h   = blockIdx.y;
    const int bm0 = blockIdx.x * 256;
    const int b   = bm0 >> 10;
    const int m0  = bm0 & 1023;
    const int tid = threadIdx.x;
    const int lane = tid & 63;
    const int w    = tid >> 6;
    const int l15  = lane & 15;
    const int quad = lane >> 4;

    __shared__ alignas(16) short SM[256 * 72 + 64 * 72];
    short* As = SM;
    short* Bs = SM + 256 * 72;

    f32x4 acc[4][4];
    #pragma unroll
    for (int mt = 0; mt < 4; ++mt)
        #pragma unroll
        for (int dt = 0; dt < 4; ++dt) acc[mt][dt] = (f32x4){0.f, 0.f, 0.f, 0.f};

    for (int kc = 0; kc < 4; ++kc) {
        #pragma unroll
        for (int i = 0; i < 8; ++i) {
            int u = tid + i * 256;
            int row = u >> 3;
            int cg  = (u & 7) * 8;
            *(uint4*)&As[row * 72 + cg] =
                *(const uint4*)&P[(size_t)(bm0 + row) * RR + kc * 64 + cg];
        }
        #pragma unroll
        for (int i = 0; i < 2; ++i) {
            int u = tid + i * 256;
            int row = u >> 3;
            int cg  = (u & 7) * 8;
            *(uint4*)&Bs[row * 72 + cg] =
                *(const uint4*)((const short*)VT + (size_t)(h * 64 + row) * RR + kc * 64 + cg);
        }
        __syncthreads();

        #pragma unroll
        for (int ks = 0; ks < 2; ++ks) {
            short8 a[4];
            #pragma unroll
            for (int mt = 0; mt < 4; ++mt)
                a[mt] = *(const short8*)&As[(w * 64 + mt * 16 + l15) * 72 + ks * 32 + quad * 8];
            #pragma unroll
            for (int dt = 0; dt < 4; ++dt) {
                short8 bf = *(const short8*)&Bs[(dt * 16 + l15) * 72 + ks * 32 + quad * 8];
                #pragma unroll
                for (int mt = 0; mt < 4; ++mt)
                    acc[mt][dt] = __builtin_amdgcn_mfma_f32_16x16x32_bf16(a[mt], bf, acc[mt][dt], 0, 0, 0);
            }
        }
        __syncthreads();
    }

    #pragma unroll
    for (int dt = 0; dt < 4; ++dt) {
        float bc = bias[h * 64 + dt * 16 + l15];
        #pragma unroll
        for (int mt = 0; mt < 4; ++mt)
            #pragma unroll
            for (int r = 0; r < 4; ++r) acc[mt][dt][r] += bc;
    }

    if (which < 2) {
        __hip_bfloat16* out = (which == 0) ? qout : kout;
        int pm[4][4];
        #pragma unroll
        for (int mt = 0; mt < 4; ++mt)
            #pragma unroll
            for (int r = 0; r < 4; ++r)
                pm[mt][r] = pos_ids[bm0 + w * 64 + mt * 16 + quad * 4 + r];
        float cB[2][4][4], sB[2][4][4];
        #pragma unroll
        for (int f2 = 0; f2 < 2; ++f2) {
            float invf = __powf(10000.0f, -(float)(f2 * 16 + l15) * (1.0f / 32.0f));
            #pragma unroll
            for (int mt = 0; mt < 4; ++mt)
                #pragma unroll
                for (int r = 0; r < 4; ++r) {
                    float ang = (float)pm[mt][r] * invf;
                    __sincosf(ang, &sB[f2][mt][r], &cB[f2][mt][r]);
                }
        }
        #pragma unroll
        for (int dt = 0; dt < 4; ++dt) {
            const int cd = dt * 16 + l15;
            const int f2 = dt & 1;
            #pragma unroll
            for (int mt = 0; mt < 4; ++mt)
                #pragma unroll
                for (int r = 0; r < 4; ++r) {
                    float x  = acc[mt][dt][r];
                    float xp = acc[mt][dt ^ 2][r];
                    float c = cB[f2][mt][r], s = sB[f2][mt][r];
                    float val = (dt < 2) ? (x * c - xp * s) : (xp * s + x * c);
                    int m = m0 + w * 64 + mt * 16 + quad * 4 + r;
                    out[(((size_t)b * HH + h) * MM + m) * DHH + cd] = __float2bfloat16(val);
                }
        }
    } else {
        short* Tt = SM;
        __syncthreads();
        #pragma unroll
        for (int dt = 0; dt < 4; ++dt)
            #pragma unroll
            for (int mt = 0; mt < 4; ++mt) {
                union { unsigned short u[4]; uint2 v; } pk;
                #pragma unroll
                for (int r = 0; r < 4; ++r) pk.u[r] = f2bf(acc[mt][dt][r]);
                *(uint2*)&Tt[(dt * 16 + l15) * 264 + w * 64 + mt * 16 + quad * 4] = pk.v;
            }
        __syncthreads();
        #pragma unroll
        for (int it = 0; it < 8; ++it) {
            int u = tid + it * 256;
            int row = u >> 5;
            int seg = u & 31;
            *(uint4*)&vTout[(((size_t)b * HH + h) * DHH + row) * MM + m0 + seg * 8] =
                *(const uint4*)&Tt[row * 264 + seg * 8];
        }
    }
}

// ---------------- Kernel C: flash attention (K via LDS-DMA, V in registers) ----------------
// grid = 512: blockIdx = qt*64 + bh (qt 0..7, 128 queries/block; bh%8 -> XCD locality).
// R8 lesson: per-chunk cost is a fixed ~9.3k-cycle serialization -> minimize what each
// iteration's barrier couples. V no longer goes through LDS at all: each wave loads its
// PV B-frags DIRECTLY from global vT (R4-verified address algebra: slot j=0..3 ->
// n=32p+quad*4+j, j=4..7 -> +16), double-buffered in REGISTERS via loop-unroll (vA/vB,
// static indices per rule #20), prefetched one chunk ahead (half at chunk top, half after
// PV p=1 to keep VGPR peak ~236). K path unchanged from R7: async global_load_lds with
// XOR-source swizzle, LDS dbuf, 1 barrier/chunk (now guarding ONLY K), setprio,
// MFMA denominator (pa x ones), full-mask fast path.
__global__ __launch_bounds__(256, 2) void attn_kernel(
    const __hip_bfloat16* __restrict__ q, const __hip_bfloat16* __restrict__ k,
    const __hip_bfloat16* __restrict__ vT,
    const int* __restrict__ mask, float* __restrict__ out)
{
    const int bh   = blockIdx.x & 63;
    const int qt   = blockIdx.x >> 6;         // 0..7
    const int b    = bh >> 4;
    const int tid  = threadIdx.x;
    const int lane = tid & 63;
    const int w    = tid >> 6;
    const int l15  = lane & 15;
    const int quad = lane >> 4;
    const int q0   = qt * 128;

    __shared__ alignas(16) short KtL[2][128 * 64];           // linear, dbuf, 32 KB total

    const short* kbase = (const short*)k  + (size_t)bh * MM * DHH;
    const short* vbase = (const short*)vT + (size_t)bh * DHH * MM;
    const short* vrow  = vbase + (size_t)l15 * MM + quad * 4;   // per-lane V B-frag base

    // Q B-frags: 2 m-tiles per wave
    short8 qa[2][2];
    #pragma unroll
    for (int mt = 0; mt < 2; ++mt) {
        const short* qb = (const short*)q +
            ((size_t)bh * MM + q0 + w * 32 + mt * 16 + l15) * DHH + quad * 8;
        qa[mt][0] = *(const short8*)(qb);
        qa[mt][1] = *(const short8*)(qb + 32);
    }

    // ones B-frag (bf16 1.0) for the denominator MFMA
    short8 onesB;
    #pragma unroll
    for (int i = 0; i < 8; ++i) onesB[i] = (short)0x3F80;

    f32x4 Ot[2][4];
    f32x4 Lacc[2];
    #pragma unroll
    for (int mt = 0; mt < 2; ++mt) {
        #pragma unroll
        for (int dt = 0; dt < 4; ++dt) Ot[mt][dt] = (f32x4){0.f, 0.f, 0.f, 0.f};
        Lacc[mt] = (f32x4){0.f, 0.f, 0.f, 0.f};
    }

    const int* maskb = mask + b * MM;
    const float k2 = 0.125f * 1.44269504089f;               // scale * log2(e)

    // K-frag physical granule indices (swizzle g^(row&7); row&7 == l15&7) — loop-invariant
    const int p0 = quad ^ (l15 & 7);
    const int p1 = (quad + 4) ^ (l15 & 7);

    // V register double-buffer (named -> static indices)
    short8 vA[4][4], vB[4][4];

    // load 2 p-slices (8 frags) of a V chunk into regs: 16x global_load_dwordx2
    auto vload2 = [&](short8 (&v)[4][4], int pbase, int n0) {
        #pragma unroll
        for (int p = 0; p < 2; ++p)
            #pragma unroll
            for (int dt = 0; dt < 4; ++dt) {
                const short* a = vrow + (size_t)dt * 16 * MM + n0 + (pbase + p) * 32;
                union { uint2 h2[2]; short8 s; } u;
                u.h2[0] = *(const uint2*)(a);
                u.h2[1] = *(const uint2*)(a + 16);
                v[pbase + p][dt] = u.s;
            }
    };

    // ---- prologue: K chunk 0 via DMA into KtL[0]; V chunk 0 fully into vA ----
    {
        #pragma unroll
        for (int pass = 0; pass < 4; ++pass) {
            int u = tid + pass * 256;            // dest granule (16B), linear
            int row = u >> 3;
            int gl  = (u & 7) ^ (row & 7);       // logical granule stored here
            gload_lds16(kbase + (size_t)row * DHH + gl * 8, &KtL[0][u * 8]);
        }
        vload2(vA, 0, 0);
        vload2(vA, 2, 0);
        __syncthreads();
    }

    // one 128-key chunk; reads Kr + vc, prefetches next chunk into Kw + vn
    auto chunk = [&](int n0, const short* Kr, short* Kw,
                     short8 (&vc)[4][4], short8 (&vn)[4][4]) {
        const bool pf = (n0 + 128) < MM;
        if (pf) {
            vload2(vn, 0, n0 + 128);             // first half of next V
            const short* kb2 = kbase + (size_t)(n0 + 128) * DHH;
            #pragma unroll
            for (int pass = 0; pass < 4; ++pass) {
                int u = tid + pass * 256;
                int row = u >> 3;
                int gl  = (u & 7) ^ (row & 7);
                gload_lds16(kb2 + (size_t)row * DHH + gl * 8, Kw + (size_t)u * 8);
            }
        }

        unsigned long long bal0 = __ballot(maskb[n0 + lane] != 0);
        unsigned long long bal1 = __ballot(maskb[n0 + 64 + lane] != 0);

        // ---- S^T = K·Q^T : 8 n-subtiles from LDS K ----
        f32x4 S[2][8];
        __builtin_amdgcn_s_setprio(1);
        #pragma unroll
        for (int t = 0; t < 8; ++t) {
            const short* krow = Kr + (size_t)(t * 16 + l15) * 64;
            short8 ka0 = *(const short8*)(krow + p0 * 8);
            short8 ka1 = *(const short8*)(krow + p1 * 8);
            #pragma unroll
            for (int mt = 0; mt < 2; ++mt) {
                f32x4 c = (f32x4){0.f, 0.f, 0.f, 0.f};
                c = __builtin_amdgcn_mfma_f32_16x16x32_bf16(ka0, qa[mt][0], c, 0, 0, 0);
                c = __builtin_amdgcn_mfma_f32_16x16x32_bf16(ka1, qa[mt][1], c, 0, 0, 0);
                S[mt][t] = c;
            }
        }
        __builtin_amdgcn_s_setprio(0);

        // ---- exp2-domain softmax (no max-shift; |S*scale| small), in-place ----
        if ((bal0 & bal1) == ~0ull) {
            #pragma unroll
            for (int t = 0; t < 8; ++t)
                #pragma unroll
                for (int r = 0; r < 4; ++r)
                    #pragma unroll
                    for (int mt = 0; mt < 2; ++mt)
                        S[mt][t][r] = EXP2F(S[mt][t][r] * k2);
        } else {
            #pragma unroll
            for (int t = 0; t < 8; ++t) {
                unsigned bits = (unsigned)((t < 4 ? bal0 : bal1) >> ((t & 3) * 16 + quad * 4));
                #pragma unroll
                for (int r = 0; r < 4; ++r) {
                    float sb = ((bits >> r) & 1u) ? 0.0f : -1e30f;
                    #pragma unroll
                    for (int mt = 0; mt < 2; ++mt)
                        S[mt][t][r] = EXP2F(fmaf(S[mt][t][r], k2, sb));
                }
            }
        }

        // ---- pack P A-frags in-lane (k-slot-permuted; V reg layout compensates) ----
        short8 pa[2][4];
        #pragma unroll
        for (int mt = 0; mt < 2; ++mt)
            #pragma unroll
            for (int p = 0; p < 4; ++p) {
                union { unsigned u[4]; short8 s; } pk;
                pk.u[0] = pack_bf16_rh(S[mt][2*p][0],   S[mt][2*p][1]);
                pk.u[1] = pack_bf16_rh(S[mt][2*p][2],   S[mt][2*p][3]);
                pk.u[2] = pack_bf16_rh(S[mt][2*p+1][0], S[mt][2*p+1][1]);
                pk.u[3] = pack_bf16_rh(S[mt][2*p+1][2], S[mt][2*p+1][3]);
                pa[mt][p] = pk.s;
            }

        // ---- O += P·V (pure register MFMA), denominator += P·1 ----
        __builtin_amdgcn_s_setprio(1);
        #pragma unroll
        for (int p = 0; p < 2; ++p) {
            #pragma unroll
            for (int dt = 0; dt < 4; ++dt)
                #pragma unroll
                for (int mt = 0; mt < 2; ++mt)
                    Ot[mt][dt] = __builtin_amdgcn_mfma_f32_16x16x32_bf16(pa[mt][p], vc[p][dt], Ot[mt][dt], 0, 0, 0);
            #pragma unroll
            for (int mt = 0; mt < 2; ++mt)
                Lacc[mt] = __builtin_amdgcn_mfma_f32_16x16x32_bf16(pa[mt][p], onesB, Lacc[mt], 0, 0, 0);
        }
        __builtin_amdgcn_s_setprio(0);

        if (pf) vload2(vn, 2, n0 + 128);         // second half of next V (vc[0..1] now dead)

        __builtin_amdgcn_s_setprio(1);
        #pragma unroll
        for (int p = 2; p < 4; ++p) {
            #pragma unroll
            for (int dt = 0; dt < 4; ++dt)
                #pragma unroll
                for (int mt = 0; mt < 2; ++mt)
                    Ot[mt][dt] = __builtin_amdgcn_mfma_f32_16x16x32_bf16(pa[mt][p], vc[p][dt], Ot[mt][dt], 0, 0, 0);
            #pragma unroll
            for (int mt = 0; mt < 2; ++mt)
                Lacc[mt] = __builtin_amdgcn_mfma_f32_16x16x32_bf16(pa[mt][p], onesB, Lacc[mt], 0, 0, 0);
        }
        __builtin_amdgcn_s_setprio(0);

        __syncthreads();   // implicit vmcnt(0): K-DMA (and V prefetch) for n+1 landed
    };

    #pragma unroll 1
    for (int it = 0; it < 4; ++it) {
        chunk(it * 256,       KtL[0], KtL[1], vA, vB);
        chunk(it * 256 + 128, KtL[1], KtL[0], vB, vA);
    }

    // ---- epilogue: Lacc rows align with Ot rows — no shuffles needed ----
    #pragma unroll
    for (int mt = 0; mt < 2; ++mt) {
        float* ob = out + ((size_t)bh * MM + q0 + w * 32 + mt * 16) * DHH;
        #pragma unroll
        for (int r = 0; r < 4; ++r) {
            float ir = 1.0f / Lacc[mt][r];    // denominator for query row quad*4+r
            #pragma unroll
            for (int dt = 0; dt < 4; ++dt)
                ob[(quad * 4 + r) * DHH + dt * 16 + l15] = Ot[mt][dt][r] * ir;
        }
    }
}

extern "C" void kernel_launch(void* const* d_in, const int* in_sizes, int n_in,
                              void* d_out, int out_size, void* d_ws, size_t ws_size,
                              hipStream_t stream) {
    const float* Pq = (const float*)d_in[0];
    const float* Pk = (const float*)d_in[1];
    const float* Pv = (const float*)d_in[2];
    const float* Vq = (const float*)d_in[3];
    const float* Vk = (const float*)d_in[4];
    const float* Vv = (const float*)d_in[5];
    const float* bq = (const float*)d_in[6];
    const float* bk = (const float*)d_in[7];
    const float* bv = (const float*)d_in[8];
    const int* mask = (const int*)d_in[9];
    const int* pos  = (const int*)d_in[10];
    float* out = (float*)d_out;

    const size_t qkv_elems = (size_t)BB * HH * MM * DHH;
    __hip_bfloat16* qb  = (__hip_bfloat16*)d_ws;
    __hip_bfloat16* kb  = qb + qkv_elems;
    __hip_bfloat16* vT  = kb + qkv_elems;
    __hip_bfloat16* VTq = vT + qkv_elems;
    __hip_bfloat16* VTk = VTq + (size_t)DD * RR;
    __hip_bfloat16* VTv = VTk + (size_t)DD * RR;
    __hip_bfloat16* Pb  = VTv + (size_t)DD * RR;

    prep_kernel<<<768 + 3 * BB * MM * RR / 4 / 256, 256, 0, stream>>>(
        Pq, Pk, Pv, Vq, Vk, Vv, VTq, VTk, VTv, Pb);

    dim3 gG(BB * MM / 256, HH, 3);
    svd_gemm<<<gG, 256, 0, stream>>>(Pb, VTq, VTk, VTv, bq, bk, bv, pos, qb, kb, vT);

    // 512 blocks: 8 q-tiles x 64 bh
    attn_kernel<<<BB * HH * (MM / 128), 256, 0, stream>>>(qb, kb, vT, mask, out);
}

// Round 10
// 128.871 us; speedup vs baseline: 1.6121x; 1.6121x over previous
//
#include <hip/hip_runtime.h>
#include <hip/hip_bf16.h>
#include <math.h>

#define BB 4
#define MM 1024
#define RR 256
#define HH 16
#define DHH 64
#define DD (HH*DHH)   // 1024

typedef __attribute__((ext_vector_type(8))) short short8;   // 8 bf16 (MFMA A/B frag)
typedef __attribute__((ext_vector_type(4))) float f32x4;    // MFMA C/D frag

static __device__ __forceinline__ unsigned short f2bf(float x) {
    __hip_bfloat16 h = __float2bfloat16(x);
    return *(unsigned short*)&h;
}

#if defined(__has_builtin)
#  if __has_builtin(__builtin_amdgcn_exp2f)
#    define EXP2F(x) __builtin_amdgcn_exp2f(x)
#  endif
#endif
#ifndef EXP2F
#  define EXP2F(x) __expf((x) * 0.6931471805599453f)
#endif

// pack two fp32 -> bf16x2 via round-half-up + v_perm (3 VALU total)
static __device__ __forceinline__ unsigned pack_bf16_rh(float a, float b) {
    unsigned ua = __builtin_bit_cast(unsigned, a) + 0x8000u;
    unsigned ub = __builtin_bit_cast(unsigned, b) + 0x8000u;
    return __builtin_amdgcn_perm(ub, ua, 0x07060302u);   // {lo=ua[31:16], hi=ub[31:16]}
}

// async global->LDS DMA, 16B per lane; dest = wave-uniform base + lane*16 (linear!)
static __device__ __forceinline__ void gload_lds16(const void* g, void* l) {
    __builtin_amdgcn_global_load_lds(
        (const __attribute__((address_space(1))) unsigned int*)g,
        (__attribute__((address_space(3))) unsigned int*)l, 16, 0, 0);
}

// ---------------- Kernel A: prep = V-transpose (blocks 0..767) + P fp32->bf16 (rest) ----
__global__ __launch_bounds__(256) void prep_kernel(
    const float* __restrict__ Pq, const float* __restrict__ Pk, const float* __restrict__ Pv,
    const float* __restrict__ Vq, const float* __restrict__ Vk, const float* __restrict__ Vv,
    __hip_bfloat16* __restrict__ VTq, __hip_bfloat16* __restrict__ VTk,
    __hip_bfloat16* __restrict__ VTv, __hip_bfloat16* __restrict__ Pb)
{
    const int t = threadIdx.x;
    if (blockIdx.x < 768) {
        const int z   = blockIdx.x / 256;
        const int rem = blockIdx.x % 256;
        const int r0  = (rem & 7) * 32;
        const int d0  = (rem >> 3) * 32;
        const float* V = (z == 0) ? Vq : (z == 1) ? Vk : Vv;
        __hip_bfloat16* VT = (z == 0) ? VTq : (z == 1) ? VTk : VTv;

        __shared__ __hip_bfloat16 Ts[32][33];
        {
            const int row = t >> 3;
            const int c4  = (t & 7) * 4;
            float4 f = *(const float4*)&V[(size_t)(r0 + row) * DD + d0 + c4];
            Ts[row][c4 + 0] = __float2bfloat16(f.x);
            Ts[row][c4 + 1] = __float2bfloat16(f.y);
            Ts[row][c4 + 2] = __float2bfloat16(f.z);
            Ts[row][c4 + 3] = __float2bfloat16(f.w);
        }
        __syncthreads();
        {
            const int orow = t >> 3;
            const int oc4  = (t & 7) * 4;
            union { unsigned short u[4]; uint2 v; } pk;
            #pragma unroll
            for (int i = 0; i < 4; ++i) pk.u[i] = *(unsigned short*)&Ts[oc4 + i][orow];
            *(uint2*)&VT[(size_t)(d0 + orow) * RR + r0 + oc4] = pk.v;
        }
    } else {
        const size_t n4 = (size_t)BB * MM * RR / 4;
        size_t i = (size_t)(blockIdx.x - 768) * 256 + t;
        const int which = (int)(i / n4);
        const size_t off = i - (size_t)which * n4;
        const float* P = (which == 0) ? Pq : (which == 1) ? Pk : Pv;
        float4 f = *(const float4*)(P + off * 4);
        union { unsigned short u[4]; uint2 v; } pk;
        pk.u[0] = f2bf(f.x); pk.u[1] = f2bf(f.y); pk.u[2] = f2bf(f.z); pk.u[3] = f2bf(f.w);
        *(uint2*)((unsigned short*)Pb + (size_t)which * BB * MM * RR + off * 4) = pk.v;
    }
}

// ---------------- Kernel B: MFMA projection + bias + RoPE (round-0 version) ----------
__global__ __launch_bounds__(256) void svd_gemm(
    const __hip_bfloat16* __restrict__ Pb,
    const __hip_bfloat16* __restrict__ VTq, const __hip_bfloat16* __restrict__ VTk,
    const __hip_bfloat16* __restrict__ VTv,
    const float* __restrict__ bq, const float* __restrict__ bk, const float* __restrict__ bv,
    const int* __restrict__ pos_ids,
    __hip_bfloat16* __restrict__ qout, __hip_bfloat16* __restrict__ kout,
    __hip_bfloat16* __restrict__ vTout)
{
    const int which = blockIdx.z;
    const short* P = (const short*)Pb + (size_t)which * BB * MM * RR;
    const __hip_bfloat16* VT = (which == 0) ? VTq : (which == 1) ? VTk : VTv;
    const float* bias        = (which == 0) ? bq : (which == 1) ? bk : bv;

    const int h   = blockIdx.y;
    const int bm0 = blockIdx.x * 256;
    const int b   = bm0 >> 10;
    const int m0  = bm0 & 1023;
    const int tid = threadIdx.x;
    const int lane = tid & 63;
    const int w    = tid >> 6;
    const int l15  = lane & 15;
    const int quad = lane >> 4;

    __shared__ alignas(16) short SM[256 * 72 + 64 * 72];
    short* As = SM;
    short* Bs = SM + 256 * 72;

    f32x4 acc[4][4];
    #pragma unroll
    for (int mt = 0; mt < 4; ++mt)
        #pragma unroll
        for (int dt = 0; dt < 4; ++dt) acc[mt][dt] = (f32x4){0.f, 0.f, 0.f, 0.f};

    for (int kc = 0; kc < 4; ++kc) {
        #pragma unroll
        for (int i = 0; i < 8; ++i) {
            int u = tid + i * 256;
            int row = u >> 3;
            int cg  = (u & 7) * 8;
            *(uint4*)&As[row * 72 + cg] =
                *(const uint4*)&P[(size_t)(bm0 + row) * RR + kc * 64 + cg];
        }
        #pragma unroll
        for (int i = 0; i < 2; ++i) {
            int u = tid + i * 256;
            int row = u >> 3;
            int cg  = (u & 7) * 8;
            *(uint4*)&Bs[row * 72 + cg] =
                *(const uint4*)((const short*)VT + (size_t)(h * 64 + row) * RR + kc * 64 + cg);
        }
        __syncthreads();

        #pragma unroll
        for (int ks = 0; ks < 2; ++ks) {
            short8 a[4];
            #pragma unroll
            for (int mt = 0; mt < 4; ++mt)
                a[mt] = *(const short8*)&As[(w * 64 + mt * 16 + l15) * 72 + ks * 32 + quad * 8];
            #pragma unroll
            for (int dt = 0; dt < 4; ++dt) {
                short8 bf = *(const short8*)&Bs[(dt * 16 + l15) * 72 + ks * 32 + quad * 8];
                #pragma unroll
                for (int mt = 0; mt < 4; ++mt)
                    acc[mt][dt] = __builtin_amdgcn_mfma_f32_16x16x32_bf16(a[mt], bf, acc[mt][dt], 0, 0, 0);
            }
        }
        __syncthreads();
    }

    #pragma unroll
    for (int dt = 0; dt < 4; ++dt) {
        float bc = bias[h * 64 + dt * 16 + l15];
        #pragma unroll
        for (int mt = 0; mt < 4; ++mt)
            #pragma unroll
            for (int r = 0; r < 4; ++r) acc[mt][dt][r] += bc;
    }

    if (which < 2) {
        __hip_bfloat16* out = (which == 0) ? qout : kout;
        int pm[4][4];
        #pragma unroll
        for (int mt = 0; mt < 4; ++mt)
            #pragma unroll
            for (int r = 0; r < 4; ++r)
                pm[mt][r] = pos_ids[bm0 + w * 64 + mt * 16 + quad * 4 + r];
        float cB[2][4][4], sB[2][4][4];
        #pragma unroll
        for (int f2 = 0; f2 < 2; ++f2) {
            float invf = __powf(10000.0f, -(float)(f2 * 16 + l15) * (1.0f / 32.0f));
            #pragma unroll
            for (int mt = 0; mt < 4; ++mt)
                #pragma unroll
                for (int r = 0; r < 4; ++r) {
                    float ang = (float)pm[mt][r] * invf;
                    __sincosf(ang, &sB[f2][mt][r], &cB[f2][mt][r]);
                }
        }
        #pragma unroll
        for (int dt = 0; dt < 4; ++dt) {
            const int cd = dt * 16 + l15;
            const int f2 = dt & 1;
            #pragma unroll
            for (int mt = 0; mt < 4; ++mt)
                #pragma unroll
                for (int r = 0; r < 4; ++r) {
                    float x  = acc[mt][dt][r];
                    float xp = acc[mt][dt ^ 2][r];
                    float c = cB[f2][mt][r], s = sB[f2][mt][r];
                    float val = (dt < 2) ? (x * c - xp * s) : (xp * s + x * c);
                    int m = m0 + w * 64 + mt * 16 + quad * 4 + r;
                    out[(((size_t)b * HH + h) * MM + m) * DHH + cd] = __float2bfloat16(val);
                }
        }
    } else {
        short* Tt = SM;
        __syncthreads();
        #pragma unroll
        for (int dt = 0; dt < 4; ++dt)
            #pragma unroll
            for (int mt = 0; mt < 4; ++mt) {
                union { unsigned short u[4]; uint2 v; } pk;
                #pragma unroll
                for (int r = 0; r < 4; ++r) pk.u[r] = f2bf(acc[mt][dt][r]);
                *(uint2*)&Tt[(dt * 16 + l15) * 264 + w * 64 + mt * 16 + quad * 4] = pk.v;
            }
        __syncthreads();
        #pragma unroll
        for (int it = 0; it < 8; ++it) {
            int u = tid + it * 256;
            int row = u >> 5;
            int seg = u & 31;
            *(uint4*)&vTout[(((size_t)b * HH + h) * DHH + row) * MM + m0 + seg * 8] =
                *(const uint4*)&Tt[row * 264 + seg * 8];
        }
    }
}

// ---------------- Kernel C: flash attention (R7 = best measured: 129.3 µs total) --------
// grid = 512: blockIdx = qt*64 + bh (qt 0..7, 128 queries/block; bh%8 -> XCD locality).
// K via global_load_lds (async DMA, XOR-source swizzle, linear LDS dest), V reg-staged
// issue-early/write-late (T14), 1 barrier/chunk, setprio around MFMA clusters,
// MFMA-computed softmax denominator (pa x ones -> rows align with Ot, shuffle-free
// epilogue), wave-uniform full-mask fast path.
// R8 (64-key chunks) and R9 (V-in-registers from global) both regressed:
// per-chunk cost is latency-fixed, and scattered per-lane V gathers over-fetch 8x.
__global__ __launch_bounds__(256, 2) void attn_kernel(
    const __hip_bfloat16* __restrict__ q, const __hip_bfloat16* __restrict__ k,
    const __hip_bfloat16* __restrict__ vT,
    const int* __restrict__ mask, float* __restrict__ out)
{
    const int bh   = blockIdx.x & 63;
    const int qt   = blockIdx.x >> 6;         // 0..7
    const int b    = bh >> 4;
    const int tid  = threadIdx.x;
    const int lane = tid & 63;
    const int w    = tid >> 6;
    const int l15  = lane & 15;
    const int quad = lane >> 4;
    const int q0   = qt * 128;

    __shared__ alignas(16) short KtL[2][128 * 64];           // linear, dbuf, 32 KB
    __shared__ alignas(16) __hip_bfloat16 Vt[2][64][136];    // permuted, dbuf, 34.8 KB

    const short* kbase = (const short*)k  + (size_t)bh * MM * DHH;
    const short* vbase = (const short*)vT + (size_t)bh * DHH * MM;

    // Q B-frags: 2 m-tiles per wave
    short8 qa[2][2];
    #pragma unroll
    for (int mt = 0; mt < 2; ++mt) {
        const short* qb = (const short*)q +
            ((size_t)bh * MM + q0 + w * 32 + mt * 16 + l15) * DHH + quad * 8;
        qa[mt][0] = *(const short8*)(qb);
        qa[mt][1] = *(const short8*)(qb + 32);
    }

    // ones B-frag (bf16 1.0) for the denominator MFMA
    short8 onesB;
    #pragma unroll
    for (int i = 0; i < 8; ++i) onesB[i] = (short)0x3F80;

    f32x4 Ot[2][4];
    f32x4 Lacc[2];
    #pragma unroll
    for (int mt = 0; mt < 2; ++mt) {
        #pragma unroll
        for (int dt = 0; dt < 4; ++dt) Ot[mt][dt] = (f32x4){0.f, 0.f, 0.f, 0.f};
        Lacc[mt] = (f32x4){0.f, 0.f, 0.f, 0.f};
    }

    const int* maskb = mask + b * MM;
    const float k2 = 0.125f * 1.44269504089f;               // scale * log2(e)

    // K-frag physical granule indices (swizzle g^(row&7); row&7 == l15&7) — loop-invariant
    const int p0 = quad ^ (l15 & 7);
    const int p1 = (quad + 4) ^ (l15 & 7);

    // ---- prologue: stage chunk 0 into buffer 0 ----
    {
        #pragma unroll
        for (int pass = 0; pass < 4; ++pass) {
            int u = tid + pass * 256;            // dest granule (16B), linear
            int row = u >> 3;
            int gl  = (u & 7) ^ (row & 7);       // logical granule stored here
            gload_lds16(kbase + (size_t)row * DHH + gl * 8, &KtL[0][u * 8]);
        }
        #pragma unroll
        for (int pass = 0; pass < 4; ++pass) {
            int u = tid + pass * 256;
            int row = u >> 4, c = u & 15;
            union { uint4 q4; uint2 h2[2]; } vld;
            vld.q4 = *(const uint4*)(vbase + (size_t)row * MM + c * 8);
            int g = c >> 3, c6 = c & 7;
            int base0 = g * 64 + (c6 >> 2) * 32 + (c6 & 1) * 16 + ((c6 >> 1) & 1) * 4;
            *(uint2*)&Vt[0][row][base0]     = vld.h2[0];
            *(uint2*)&Vt[0][row][base0 + 8] = vld.h2[1];
        }
        __syncthreads();
    }

    for (int nc = 0; nc < MM / 128; ++nc) {
        const int cur = nc & 1;
        const int n0  = nc * 128;

        // ---- issue next chunk's staging: V to regs first, then K async DMA ----
        uint4 vreg[4];
        if (nc < 7) {
            const short* vb2 = vbase + n0 + 128;
            #pragma unroll
            for (int pass = 0; pass < 4; ++pass) {
                int u = tid + pass * 256, row = u >> 4, c = u & 15;
                vreg[pass] = *(const uint4*)(vb2 + (size_t)row * MM + c * 8);
            }
            const short* kb2 = kbase + (size_t)(n0 + 128) * DHH;
            #pragma unroll
            for (int pass = 0; pass < 4; ++pass) {
                int u = tid + pass * 256;
                int row = u >> 3;
                int gl  = (u & 7) ^ (row & 7);
                gload_lds16(kb2 + (size_t)row * DHH + gl * 8, &KtL[cur ^ 1][u * 8]);
            }
        }

        unsigned long long bal0 = __ballot(maskb[n0 + lane] != 0);
        unsigned long long bal1 = __ballot(maskb[n0 + 64 + lane] != 0);

        // ---- S^T = K·Q^T : 8 n-subtiles, lane l15 = m, reg (t, quad*4+r) = n ----
        f32x4 S[2][8];
        __builtin_amdgcn_s_setprio(1);
        #pragma unroll
        for (int t = 0; t < 8; ++t) {
            const short* krow = &KtL[cur][(t * 16 + l15) * 64];
            short8 ka0 = *(const short8*)(krow + p0 * 8);
            short8 ka1 = *(const short8*)(krow + p1 * 8);
            #pragma unroll
            for (int mt = 0; mt < 2; ++mt) {
                f32x4 c = (f32x4){0.f, 0.f, 0.f, 0.f};
                c = __builtin_amdgcn_mfma_f32_16x16x32_bf16(ka0, qa[mt][0], c, 0, 0, 0);
                c = __builtin_amdgcn_mfma_f32_16x16x32_bf16(ka1, qa[mt][1], c, 0, 0, 0);
                S[mt][t] = c;
            }
        }
        __builtin_amdgcn_s_setprio(0);

        // ---- exp2-domain softmax (no max-shift; |S*scale| small), in-place ----
        if ((bal0 & bal1) == ~0ull) {
            // fast path: all keys valid — no bias extraction
            #pragma unroll
            for (int t = 0; t < 8; ++t)
                #pragma unroll
                for (int r = 0; r < 4; ++r)
                    #pragma unroll
                    for (int mt = 0; mt < 2; ++mt)
                        S[mt][t][r] = EXP2F(S[mt][t][r] * k2);
        } else {
            #pragma unroll
            for (int t = 0; t < 8; ++t) {
                unsigned bits = (unsigned)((t < 4 ? bal0 : bal1) >> ((t & 3) * 16 + quad * 4));
                #pragma unroll
                for (int r = 0; r < 4; ++r) {
                    float sb = ((bits >> r) & 1u) ? 0.0f : -1e30f;
                    #pragma unroll
                    for (int mt = 0; mt < 2; ++mt)
                        S[mt][t][r] = EXP2F(fmaf(S[mt][t][r], k2, sb));
                }
            }
        }

        // ---- pack P A-frags in-lane (k-slot-permuted to match Vt) ----
        short8 pa[2][4];
        #pragma unroll
        for (int mt = 0; mt < 2; ++mt)
            #pragma unroll
            for (int p = 0; p < 4; ++p) {
                union { unsigned u[4]; short8 s; } pk;
                pk.u[0] = pack_bf16_rh(S[mt][2*p][0],   S[mt][2*p][1]);
                pk.u[1] = pack_bf16_rh(S[mt][2*p][2],   S[mt][2*p][3]);
                pk.u[2] = pack_bf16_rh(S[mt][2*p+1][0], S[mt][2*p+1][1]);
                pk.u[3] = pack_bf16_rh(S[mt][2*p+1][2], S[mt][2*p+1][3]);
                pa[mt][p] = pk.s;
            }

        // ---- O += P·V (and denominator += P·1) : b128 B-frags from permuted Vt ----
        __builtin_amdgcn_s_setprio(1);
        #pragma unroll
        for (int p = 0; p < 4; ++p) {
            #pragma unroll
            for (int dt = 0; dt < 4; ++dt) {
                short8 vb = *(const short8*)&Vt[cur][dt * 16 + l15][p * 32 + quad * 8];
                #pragma unroll
                for (int mt = 0; mt < 2; ++mt)
                    Ot[mt][dt] = __builtin_amdgcn_mfma_f32_16x16x32_bf16(pa[mt][p], vb, Ot[mt][dt], 0, 0, 0);
            }
            #pragma unroll
            for (int mt = 0; mt < 2; ++mt)
                Lacc[mt] = __builtin_amdgcn_mfma_f32_16x16x32_bf16(pa[mt][p], onesB, Lacc[mt], 0, 0, 0);
        }
        __builtin_amdgcn_s_setprio(0);

        // ---- drain V prefetch (permuted) into the other buffer ----
        if (nc < 7) {
            #pragma unroll
            for (int pass = 0; pass < 4; ++pass) {
                int u = tid + pass * 256, row = u >> 4, c = u & 15;
                union { uint4 q4; uint2 h2[2]; } vld;
                vld.q4 = vreg[pass];
                int g = c >> 3, c6 = c & 7;
                int base0 = g * 64 + (c6 >> 2) * 32 + (c6 & 1) * 16 + ((c6 >> 1) & 1) * 4;
                *(uint2*)&Vt[cur ^ 1][row][base0]     = vld.h2[0];
                *(uint2*)&Vt[cur ^ 1][row][base0 + 8] = vld.h2[1];
            }
        }
        __syncthreads();   // implicit vmcnt(0): K-DMA for chunk n+1 has landed
    }

    // ---- epilogue: Lacc rows align with Ot rows — no shuffles needed ----
    #pragma unroll
    for (int mt = 0; mt < 2; ++mt) {
        float* ob = out + ((size_t)bh * MM + q0 + w * 32 + mt * 16) * DHH;
        #pragma unroll
        for (int r = 0; r < 4; ++r) {
            float ir = 1.0f / Lacc[mt][r];    // denominator for query row quad*4+r
            #pragma unroll
            for (int dt = 0; dt < 4; ++dt)
                ob[(quad * 4 + r) * DHH + dt * 16 + l15] = Ot[mt][dt][r] * ir;
        }
    }
}

extern "C" void kernel_launch(void* const* d_in, const int* in_sizes, int n_in,
                              void* d_out, int out_size, void* d_ws, size_t ws_size,
                              hipStream_t stream) {
    const float* Pq = (const float*)d_in[0];
    const float* Pk = (const float*)d_in[1];
    const float* Pv = (const float*)d_in[2];
    const float* Vq = (const float*)d_in[3];
    const float* Vk = (const float*)d_in[4];
    const float* Vv = (const float*)d_in[5];
    const float* bq = (const float*)d_in[6];
    const float* bk = (const float*)d_in[7];
    const float* bv = (const float*)d_in[8];
    const int* mask = (const int*)d_in[9];
    const int* pos  = (const int*)d_in[10];
    float* out = (float*)d_out;

    const size_t qkv_elems = (size_t)BB * HH * MM * DHH;
    __hip_bfloat16* qb  = (__hip_bfloat16*)d_ws;
    __hip_bfloat16* kb  = qb + qkv_elems;
    __hip_bfloat16* vT  = kb + qkv_elems;
    __hip_bfloat16* VTq = vT + qkv_elems;
    __hip_bfloat16* VTk = VTq + (size_t)DD * RR;
    __hip_bfloat16* VTv = VTk + (size_t)DD * RR;
    __hip_bfloat16* Pb  = VTv + (size_t)DD * RR;

    prep_kernel<<<768 + 3 * BB * MM * RR / 4 / 256, 256, 0, stream>>>(
        Pq, Pk, Pv, Vq, Vk, Vv, VTq, VTk, VTv, Pb);

    dim3 gG(BB * MM / 256, HH, 3);
    svd_gemm<<<gG, 256, 0, stream>>>(Pb, VTq, VTk, VTv, bq, bk, bv, pos, qb, kb, vT);

    // 512 blocks: 8 q-tiles x 64 bh
    attn_kernel<<<BB * HH * (MM / 128), 256, 0, stream>>>(qb, kb, vT, mask, out);
}